// Round 2
// baseline (344.693 us; speedup 1.0000x reference)
//
#include <hip/hip_runtime.h>

// ---------------------------------------------------------------------------
// Problem constants (all dims divide the tile sizes exactly -> no bounds checks)
// ---------------------------------------------------------------------------
// X:(16,4096,512) -> M=65536 rows. enc1 K=512 N=256, enc2 K=256 N=64.
// h=511 patches/batch, N_rows=8176. dec K=64 N=512.

typedef __attribute__((ext_vector_type(8))) short short8;   // 8 bf16 = 4 VGPRs (MFMA A/B frag)
typedef __attribute__((ext_vector_type(4))) float floatx4;  // MFMA C/D frag

__device__ __forceinline__ unsigned short f2bf(float f) {
    unsigned u = __float_as_uint(f);
    u += 0x7FFFu + ((u >> 16) & 1u);   // round-to-nearest-even
    return (unsigned short)(u >> 16);
}

// ---------------------------------------------------------------------------
// Prep: transpose+convert weights to bf16 K-major:  Wt[n][k] = bf16(W[k][n])
// W1t[256][512], W2t[64][256], Wdt[512][64]
// ---------------------------------------------------------------------------
__global__ __launch_bounds__(256) void prep_weights(
    const float* __restrict__ W1, const float* __restrict__ W2,
    const float* __restrict__ Wd,
    unsigned short* __restrict__ W1t, unsigned short* __restrict__ W2t,
    unsigned short* __restrict__ Wdt)
{
    int idx = blockIdx.x * 256 + threadIdx.x;           // 512 blocks -> 131072
    { int n = idx >> 9, k = idx & 511;  W1t[idx] = f2bf(W1[k * 256 + n]); } // 256x512
    if (idx < 16384) { int n = idx >> 8, k = idx & 255; W2t[idx] = f2bf(W2[k * 64 + n]); }
    if (idx < 32768) { int n = idx >> 6, k = idx & 63;  Wdt[idx] = f2bf(Wd[k * 512 + n]); }
}

// ---------------------------------------------------------------------------
// GEMM: C[M][N] = epi(A[M][K] @ Bt[N][K]^T + bias)
//   BM x BN block tile, BK=64, 256 threads = 4 waves, WM x WN per wave.
//   LDS rows padded to 72 bf16 (144 B): 16B-aligned ds_read_b128, 2-way banks.
//   EPI 0: leaky(0.01)+bias -> bf16 out.  EPI 1: +bias -> fp32 out.
// ---------------------------------------------------------------------------
template<int BM, int BN, int WM, int WN, bool AF32, int EPI>
__global__ __launch_bounds__(256) void gemm_kernel(
    const void* __restrict__ Aq, const unsigned short* __restrict__ Bt,
    const float* __restrict__ bias, void* __restrict__ Cq,
    int M, int N, int K, int lda)
{
    constexpr int LDK = 72;
    __shared__ short As[BM * LDK];
    __shared__ short Bs[BN * LDK];

    const int tid  = threadIdx.x;
    const int lane = tid & 63;
    const int w    = tid >> 6;
    constexpr int MWAVES = BM / WM;
    const int wrow = (w % MWAVES) * WM;
    const int wcol = (w / MWAVES) * WN;
    constexpr int MI = WM / 16, NI = WN / 16;
    const int m0 = blockIdx.y * BM;
    const int n0 = blockIdx.x * BN;

    floatx4 acc[MI][NI];
#pragma unroll
    for (int a = 0; a < MI; a++)
#pragma unroll
        for (int bq = 0; bq < NI; bq++) acc[a][bq] = (floatx4){0.f, 0.f, 0.f, 0.f};

    constexpr int EPTA = BM * 64 / 256;   // elems/thread for A stage (32)
    constexpr int TPRA = 64 / EPTA;
    const int arow  = tid / TPRA;
    const int akseg = (tid % TPRA) * EPTA;
    constexpr int EPTB = BN * 64 / 256;   // 32 (BN=128) or 16 (BN=64)
    constexpr int TPRB = 64 / EPTB;
    const int brow  = tid / TPRB;
    const int bkseg = (tid % TPRB) * EPTB;

    for (int kt = 0; kt < K; kt += 64) {
        // ---- stage A (convert fp32->bf16 if needed) ----
        if constexpr (AF32) {
            const float* src = (const float*)Aq + (size_t)(m0 + arow) * lda + kt + akseg;
            short* dst = &As[arow * LDK + akseg];
#pragma unroll
            for (int u = 0; u < EPTA; u += 8) {
                float4 f0 = *(const float4*)(src + u);
                float4 f1 = *(const float4*)(src + u + 4);
                short8 o;
                o[0] = (short)f2bf(f0.x); o[1] = (short)f2bf(f0.y);
                o[2] = (short)f2bf(f0.z); o[3] = (short)f2bf(f0.w);
                o[4] = (short)f2bf(f1.x); o[5] = (short)f2bf(f1.y);
                o[6] = (short)f2bf(f1.z); o[7] = (short)f2bf(f1.w);
                *(short8*)(dst + u) = o;
            }
        } else {
            const unsigned short* src = (const unsigned short*)Aq + (size_t)(m0 + arow) * lda + kt + akseg;
            short* dst = &As[arow * LDK + akseg];
#pragma unroll
            for (int u = 0; u < EPTA; u += 8)
                *(short8*)(dst + u) = *(const short8*)(src + u);
        }
        // ---- stage B (already bf16 K-major) ----
        {
            const unsigned short* src = Bt + (size_t)(n0 + brow) * K + kt + bkseg;
            short* dst = &Bs[brow * LDK + bkseg];
#pragma unroll
            for (int u = 0; u < EPTB; u += 8)
                *(short8*)(dst + u) = *(const short8*)(src + u);
        }
        __syncthreads();

#pragma unroll
        for (int ks = 0; ks < 2; ks++) {
            const int koff = ks * 32 + (lane >> 4) * 8;
            short8 af[MI], bf[NI];
#pragma unroll
            for (int mi = 0; mi < MI; mi++)
                af[mi] = *(const short8*)&As[(wrow + mi * 16 + (lane & 15)) * LDK + koff];
#pragma unroll
            for (int ni = 0; ni < NI; ni++)
                bf[ni] = *(const short8*)&Bs[(wcol + ni * 16 + (lane & 15)) * LDK + koff];
#pragma unroll
            for (int mi = 0; mi < MI; mi++)
#pragma unroll
                for (int ni = 0; ni < NI; ni++)
                    acc[mi][ni] = __builtin_amdgcn_mfma_f32_16x16x32_bf16(
                        af[mi], bf[ni], acc[mi][ni], 0, 0, 0);
        }
        __syncthreads();
    }

    // ---- epilogue: D row=(lane>>4)*4+r, col=lane&15 (m89-verified) ----
#pragma unroll
    for (int mi = 0; mi < MI; mi++) {
#pragma unroll
        for (int ni = 0; ni < NI; ni++) {
            const int col = n0 + wcol + ni * 16 + (lane & 15);
            const float bv = bias[col];
#pragma unroll
            for (int r = 0; r < 4; r++) {
                const int row = m0 + wrow + mi * 16 + (lane >> 4) * 4 + r;
                float v = acc[mi][ni][r] + bv;
                if constexpr (EPI == 0) {
                    v = v > 0.f ? v : 0.01f * v;
                    ((unsigned short*)Cq)[(size_t)row * N + col] = f2bf(v);
                } else {
                    ((float*)Cq)[(size_t)row * N + col] = v;
                }
            }
        }
    }
}

// ---------------------------------------------------------------------------
// Patch attention: one wave per patch-row n (8176 total), 4 waves/block.
//  lane = channel for mean/qkv/norm; lane = attention row i for selection.
//  Top-8 on raw M (monotone under relu∘tanh); Padé(3,2) tanh in pass 2.
// ---------------------------------------------------------------------------
#define TOP8_INS(mv) do { float _x = (mv); float _t;            \
    _t = fmaxf(s0,_x); _x = fminf(s0,_x); s0 = _t;              \
    _t = fmaxf(s1,_x); _x = fminf(s1,_x); s1 = _t;              \
    _t = fmaxf(s2,_x); _x = fminf(s2,_x); s2 = _t;              \
    _t = fmaxf(s3,_x); _x = fminf(s3,_x); s3 = _t;              \
    _t = fmaxf(s4,_x); _x = fminf(s4,_x); s4 = _t;              \
    _t = fmaxf(s5,_x); _x = fminf(s5,_x); s5 = _t;              \
    _t = fmaxf(s6,_x); _x = fminf(s6,_x); s6 = _t;              \
    s7 = fmaxf(s7,_x); } while (0)

__global__ __launch_bounds__(256) void patch_attn(
    const float* __restrict__ Xe,  const float* __restrict__ Wq,
    const float* __restrict__ Wk,  const float* __restrict__ Wv,
    const float* __restrict__ Wagg, const float* __restrict__ bagg,
    float* __restrict__ zout)
{
    __shared__ float sh[4][336];        // per wave: pp|qn|kn|v|av (64 each), 16B-aligned
    const int w    = threadIdx.x >> 6;
    const int lane = threadIdx.x & 63;
    const int n = blockIdx.x * 4 + w;   // 2044*4 = 8176 exactly
    const int b = n / 511;
    const int i = n - b * 511;
    float* pp  = &sh[w][0];
    float* qs  = pp + 64;
    float* ksm = pp + 128;
    float* vsm = pp + 192;
    float* avs = pp + 256;

    // 1. per-patch mean (lane = channel)
    const float* xb = Xe + ((size_t)(b * 4096 + i * 8)) * 64 + lane;
    float s = 0.f;
#pragma unroll
    for (int p = 0; p < 16; p++) s += xb[(size_t)p * 64];
    pp[lane] = s * 0.0625f;
    __syncthreads();

    // 2. q,k,v matvecs (lane = output channel)
    float q = 0.f, k = 0.f, v = 0.f;
#pragma unroll 4
    for (int e = 0; e < 64; e += 4) {
        float4 p4 = *(const float4*)&pp[e];
        q = fmaf(p4.x, Wq[(e+0)*64+lane], q); q = fmaf(p4.y, Wq[(e+1)*64+lane], q);
        q = fmaf(p4.z, Wq[(e+2)*64+lane], q); q = fmaf(p4.w, Wq[(e+3)*64+lane], q);
        k = fmaf(p4.x, Wk[(e+0)*64+lane], k); k = fmaf(p4.y, Wk[(e+1)*64+lane], k);
        k = fmaf(p4.z, Wk[(e+2)*64+lane], k); k = fmaf(p4.w, Wk[(e+3)*64+lane], k);
        v = fmaf(p4.x, Wv[(e+0)*64+lane], v); v = fmaf(p4.y, Wv[(e+1)*64+lane], v);
        v = fmaf(p4.z, Wv[(e+2)*64+lane], v); v = fmaf(p4.w, Wv[(e+3)*64+lane], v);
    }
    // 3. normalize q,k: qn = q/(||q||+1e-8)
    float sq = q * q, sk = k * k;
#pragma unroll
    for (int o = 1; o < 64; o <<= 1) { sq += __shfl_xor(sq, o); sk += __shfl_xor(sk, o); }
    const float qni = q / (sqrtf(sq) + 1e-8f);
    const float kni = k / (sqrtf(sk) + 1e-8f);
    qs[lane] = qni; ksm[lane] = kni; vsm[lane] = v;
    __syncthreads();

    // lane now = attention row i; own qni/kni are row coefficients.
    auto MV = [&](float kj, float qj) { return fmaf(qni, kj, -(kni * qj)); };

    // 4. pass 1: top-8 of M row via sorted insertion network
    float s0=-1e30f,s1=-1e30f,s2=-1e30f,s3=-1e30f,s4=-1e30f,s5=-1e30f,s6=-1e30f,s7=-1e30f;
#pragma unroll
    for (int j = 0; j < 64; j += 4) {
        float4 k4 = *(const float4*)&ksm[j];
        float4 q4 = *(const float4*)&qs[j];
        TOP8_INS(MV(k4.x, q4.x)); TOP8_INS(MV(k4.y, q4.y));
        TOP8_INS(MV(k4.z, q4.z)); TOP8_INS(MV(k4.w, q4.w));
    }
    // 8th-largest M; <8 positives => keep all positives (kept zeros contribute 0).
    const float teff = fmaxf(s7, 1e-37f) * (1.f - 1.2e-7f); // 1-ulp slack for recompute jitter

    // 5. pass 2: tanh (Padé 3/2, |err|<1e-5 for |x|<=0.5), mask, weighted sum
    float ssum = 0.f, av = 0.f;
#pragma unroll
    for (int j = 0; j < 64; j += 4) {
        float4 k4 = *(const float4*)&ksm[j];
        float4 q4 = *(const float4*)&qs[j];
        float4 v4 = *(const float4*)&vsm[j];
#define P2(KJ, QJ, VJ) do { float _m = MV(KJ, QJ); float _x2 = _m * _m;           \
        float _a = _m * (15.f + _x2) * __builtin_amdgcn_rcpf(fmaf(6.f, _x2, 15.f)); \
        float _am = (_m >= teff) ? _a : 0.f;                                       \
        ssum += _am; av = fmaf(_am, (VJ), av); } while (0)
        P2(k4.x, q4.x, v4.x); P2(k4.y, q4.y, v4.y);
        P2(k4.z, q4.z, v4.z); P2(k4.w, q4.w, v4.w);
#undef P2
    }
    avs[lane] = av / fmaxf(ssum, 1e-8f);   // Av[i]
    __syncthreads();

    // 6. z = leaky(Av @ Wagg + bagg)  (lane = output channel)
    float zc = bagg[lane];
#pragma unroll 4
    for (int e = 0; e < 64; e += 4) {
        float4 a4 = *(const float4*)&avs[e];
        zc = fmaf(a4.x, Wagg[(e+0)*64+lane], zc); zc = fmaf(a4.y, Wagg[(e+1)*64+lane], zc);
        zc = fmaf(a4.z, Wagg[(e+2)*64+lane], zc); zc = fmaf(a4.w, Wagg[(e+3)*64+lane], zc);
    }
    zc = zc > 0.f ? zc : 0.01f * zc;
    zout[(size_t)n * 64 + lane] = zc;
}

// ---------------------------------------------------------------------------
// Overlap-average scatter: position l is covered by patches {g-1, g} (g=l>>3),
// clipped to [0,510]; counts are exactly 1 or 2. Output bf16 for dec GEMM.
// ---------------------------------------------------------------------------
__global__ __launch_bounds__(256) void scatter_avg(
    const float* __restrict__ z, unsigned short* __restrict__ zavg)
{
    const int idx = blockIdx.x * 256 + threadIdx.x;   // 16384 blocks -> 4194304
    const int c = idx & 63;
    const int l = (idx >> 6) & 4095;
    const int b = idx >> 18;
    const int g = l >> 3;
    float s = 0.f, cnt = 0.f;
    if (g >= 1)   { s += z[((size_t)(b * 511 + g - 1)) * 64 + c]; cnt += 1.f; }
    if (g <= 510) { s += z[((size_t)(b * 511 + g)) * 64 + c];     cnt += 1.f; }
    zavg[idx] = f2bf(s / cnt);
}

// ---------------------------------------------------------------------------
// Launch
// ---------------------------------------------------------------------------
extern "C" void kernel_launch(void* const* d_in, const int* in_sizes, int n_in,
                              void* d_out, int out_size, void* d_ws, size_t ws_size,
                              hipStream_t stream)
{
    const float* X    = (const float*)d_in[0];
    const float* W1   = (const float*)d_in[1];
    const float* b1   = (const float*)d_in[2];
    const float* W2   = (const float*)d_in[3];
    const float* b2   = (const float*)d_in[4];
    const float* Wq   = (const float*)d_in[5];
    const float* Wk   = (const float*)d_in[6];
    const float* Wv   = (const float*)d_in[7];
    const float* Wagg = (const float*)d_in[8];
    const float* bagg = (const float*)d_in[9];
    const float* Wd   = (const float*)d_in[10];
    const float* bd   = (const float*)d_in[11];

    char* ws = (char*)d_ws;                                   // ~61.2 MB total
    unsigned short* hidden = (unsigned short*)(ws);           // 65536x256 bf16  33,554,432 B
    float*          Xe     = (float*)(ws + 33554432);         // 65536x64  f32   16,777,216 B
    float*          z      = (float*)(ws + 50331648);         // 8176x64   f32    2,093,056 B
    unsigned short* zavg   = (unsigned short*)(ws + 52424704);// 65536x64  bf16   8,388,608 B
    unsigned short* W1t    = (unsigned short*)(ws + 60813312);// 256x512 bf16
    unsigned short* W2t    = (unsigned short*)(ws + 61075456);// 64x256  bf16
    unsigned short* Wdt    = (unsigned short*)(ws + 61108224);// 512x64  bf16
    float* out = (float*)d_out;

    prep_weights<<<512, 256, 0, stream>>>(W1, W2, Wd, W1t, W2t, Wdt);

    // enc1: hidden = leaky(X @ W1 + b1)   [bf16 out]
    gemm_kernel<128,128,64,64,true,0><<<dim3(2,512), 256, 0, stream>>>(
        X, W1t, b1, hidden, 65536, 256, 512, 512);
    // enc2: Xe = hidden @ W2 + b2         [f32 out]
    gemm_kernel<128,64,32,64,false,1><<<dim3(1,512), 256, 0, stream>>>(
        hidden, W2t, b2, Xe, 65536, 64, 256, 256);
    // patch attention -> z
    patch_attn<<<2044, 256, 0, stream>>>(Xe, Wq, Wk, Wv, Wagg, bagg, z);
    // overlap-average -> zavg (bf16)
    scatter_avg<<<16384, 256, 0, stream>>>(z, zavg);
    // dec: out = zavg @ Wd + bd           [f32 out]
    gemm_kernel<128,128,64,64,false,1><<<dim3(4,512), 256, 0, stream>>>(
        zavg, Wdt, bd, out, 65536, 512, 64, 64);
}

// Round 3
// 341.231 us; speedup vs baseline: 1.0101x; 1.0101x over previous
//
#include <hip/hip_runtime.h>

// ---------------------------------------------------------------------------
// X:(16,4096,512) -> M=65536 rows. enc1 K=512 N=256, enc2 K=256 N=64.
// h=511 patches/batch, N_rows=8176. dec K=64 N=512.
// All GEMMs in fp16 MFMA (16x16x32_f16): same rate as bf16, 8x less quant error.
// ---------------------------------------------------------------------------

typedef __attribute__((ext_vector_type(8))) _Float16 half8;  // MFMA A/B frag (4 VGPR)
typedef __attribute__((ext_vector_type(4))) _Float16 half4;
typedef __attribute__((ext_vector_type(4))) float floatx4;   // MFMA C/D frag

__device__ __forceinline__ _Float16 f2h(float f) { return (_Float16)f; } // v_cvt_f16_f32 (RNE)

// ---------------------------------------------------------------------------
// Prep: transpose+convert weights to fp16 K-major:  Wt[n][k] = h(W[k][n])
// ---------------------------------------------------------------------------
__global__ __launch_bounds__(256) void prep_weights(
    const float* __restrict__ W1, const float* __restrict__ W2,
    const float* __restrict__ Wd,
    _Float16* __restrict__ W1t, _Float16* __restrict__ W2t,
    _Float16* __restrict__ Wdt)
{
    int idx = blockIdx.x * 256 + threadIdx.x;           // 512 blocks -> 131072
    { int n = idx >> 9, k = idx & 511;  W1t[idx] = f2h(W1[k * 256 + n]); } // 256x512
    if (idx < 16384) { int n = idx >> 8, k = idx & 255; W2t[idx] = f2h(W2[k * 64 + n]); }
    if (idx < 32768) { int n = idx >> 6, k = idx & 63;  Wdt[idx] = f2h(Wd[k * 512 + n]); }
}

// ---------------------------------------------------------------------------
// GEMM: C[M][N] = epi(A[M][K] @ Bt[N][K]^T + bias)
//  - register-prefetch double buffering over BK=64 K-tiles
//  - LDS rows padded to 72 halfs (144 B): aligned ds_read_b128, rows spread banks
//  - chunked LDS-transpose epilogue -> coalesced float4/half4 stores
//  EPI 0: leaky(0.01)+bias -> fp16 out.  EPI 1: +bias -> fp32 out.
// ---------------------------------------------------------------------------
template<int BM, int BN, int WM, int WN, bool AF32, int EPI>
__global__ __launch_bounds__(256) void gemm_kernel(
    const void* __restrict__ Aq, const _Float16* __restrict__ Bt,
    const float* __restrict__ bias, void* __restrict__ Cq,
    int M, int N, int K, int lda)
{
    constexpr int LDK = 72;
    __shared__ _Float16 As[BM * LDK];
    __shared__ _Float16 Bs[BN * LDK];
    static_assert(32 * BN * 4 <= BM * LDK * 2, "epilogue chunk must fit in As");

    const int tid  = threadIdx.x;
    const int lane = tid & 63;
    const int w    = tid >> 6;
    constexpr int MWAVES = BM / WM;
    const int wrow = (w % MWAVES) * WM;
    const int wcol = (w / MWAVES) * WN;
    constexpr int MI = WM / 16, NI = WN / 16;
    const int m0 = blockIdx.y * BM;
    const int n0 = blockIdx.x * BN;

    floatx4 acc[MI][NI];
#pragma unroll
    for (int a = 0; a < MI; a++)
#pragma unroll
        for (int bq = 0; bq < NI; bq++) acc[a][bq] = (floatx4){0.f, 0.f, 0.f, 0.f};

    constexpr int EPTA = BM * 64 / 256;   // 32
    constexpr int TPRA = 64 / EPTA;
    const int arow  = tid / TPRA;
    const int akseg = (tid % TPRA) * EPTA;
    constexpr int EPTB = BN * 64 / 256;   // 32 (BN=128) / 16 (BN=64)
    constexpr int TPRB = 64 / EPTB;
    const int brow  = tid / TPRB;
    const int bkseg = (tid % TPRB) * EPTB;

    const float*    Af = (const float*)Aq;
    const _Float16* Ah = (const _Float16*)Aq;

    // prefetch registers
    float4 pa[AF32 ? EPTA / 4 : 1];
    half8  paq[AF32 ? 1 : EPTA / 8];
    half8  pb[EPTB / 8];

    auto loadA = [&](int kt) {
        if constexpr (AF32) {
            const float* s = Af + (size_t)(m0 + arow) * lda + kt + akseg;
#pragma unroll
            for (int u = 0; u < EPTA / 4; u++) pa[u] = *(const float4*)(s + 4 * u);
        } else {
            const _Float16* s = Ah + (size_t)(m0 + arow) * lda + kt + akseg;
#pragma unroll
            for (int u = 0; u < EPTA / 8; u++) paq[u] = *(const half8*)(s + 8 * u);
        }
    };
    auto loadB = [&](int kt) {
        const _Float16* s = Bt + (size_t)(n0 + brow) * K + kt + bkseg;
#pragma unroll
        for (int u = 0; u < EPTB / 8; u++) pb[u] = *(const half8*)(s + 8 * u);
    };
    auto stage = [&]() {
        _Float16* d = &As[arow * LDK + akseg];
        if constexpr (AF32) {
#pragma unroll
            for (int u = 0; u < EPTA / 8; u++) {
                float4 f0 = pa[2 * u], f1 = pa[2 * u + 1];
                half8 o;
                o[0] = f2h(f0.x); o[1] = f2h(f0.y); o[2] = f2h(f0.z); o[3] = f2h(f0.w);
                o[4] = f2h(f1.x); o[5] = f2h(f1.y); o[6] = f2h(f1.z); o[7] = f2h(f1.w);
                *(half8*)(d + 8 * u) = o;
            }
        } else {
#pragma unroll
            for (int u = 0; u < EPTA / 8; u++) *(half8*)(d + 8 * u) = paq[u];
        }
        _Float16* db = &Bs[brow * LDK + bkseg];
#pragma unroll
        for (int u = 0; u < EPTB / 8; u++) *(half8*)(db + 8 * u) = pb[u];
    };

    loadA(0); loadB(0);
    for (int kt = 0; kt < K; kt += 64) {
        stage();                       // consumes prefetch regs (vmcnt wait here)
        __syncthreads();
        if (kt + 64 < K) { loadA(kt + 64); loadB(kt + 64); }  // overlap w/ MFMA
#pragma unroll
        for (int ks = 0; ks < 2; ks++) {
            const int koff = ks * 32 + (lane >> 4) * 8;
            half8 af[MI], bf[NI];
#pragma unroll
            for (int mi = 0; mi < MI; mi++)
                af[mi] = *(const half8*)&As[(wrow + mi * 16 + (lane & 15)) * LDK + koff];
#pragma unroll
            for (int ni = 0; ni < NI; ni++)
                bf[ni] = *(const half8*)&Bs[(wcol + ni * 16 + (lane & 15)) * LDK + koff];
#pragma unroll
            for (int mi = 0; mi < MI; mi++)
#pragma unroll
                for (int ni = 0; ni < NI; ni++)
                    acc[mi][ni] = __builtin_amdgcn_mfma_f32_16x16x32_f16(
                        af[mi], bf[ni], acc[mi][ni], 0, 0, 0);
        }
        __syncthreads();
    }

    // ---- epilogue: 32-row chunks staged fp32 in LDS -> coalesced stores ----
    float bvv[NI];
#pragma unroll
    for (int ni = 0; ni < NI; ni++) bvv[ni] = bias[n0 + wcol + ni * 16 + (lane & 15)];

    float* Cs = (float*)As;
#pragma unroll
    for (int c = 0; c < BM / 32; c++) {
        __syncthreads();
        // wave-row group owning this chunk writes (mi index is compile-time)
        constexpr int DUMMY = 0; (void)DUMMY;
        {
            const int own_wrow = ((c * 32) / WM) * WM;
            if (wrow == own_wrow) {
                constexpr int CPW = 32 < WM ? 32 : WM;  // rows this wave writes per chunk (32)
#pragma unroll
                for (int mm = 0; mm < CPW / 16; mm++) {
                    const int mi = ((c * 32) % WM) / 16 + mm;   // compile-time under unroll
#pragma unroll
                    for (int ni = 0; ni < NI; ni++) {
#pragma unroll
                        for (int r = 0; r < 4; r++) {
                            const int lr  = mm * 16 + (lane >> 4) * 4 + r;
                            const int col = wcol + ni * 16 + (lane & 15);
                            Cs[lr * BN + col] = acc[mi][ni][r] + bvv[ni];
                        }
                    }
                }
            }
        }
        __syncthreads();
#pragma unroll
        for (int u = 0; u < (32 * BN) / 1024; u++) {
            const int idx = (u * 256 + tid) * 4;
            const int lr = idx / BN, col = idx - lr * BN;
            float4 vv = *(const float4*)&Cs[idx];
            const size_t go = (size_t)(m0 + c * 32 + lr) * N + n0 + col;
            if constexpr (EPI == 0) {
                half4 hv;
                hv[0] = f2h(vv.x > 0.f ? vv.x : 0.01f * vv.x);
                hv[1] = f2h(vv.y > 0.f ? vv.y : 0.01f * vv.y);
                hv[2] = f2h(vv.z > 0.f ? vv.z : 0.01f * vv.z);
                hv[3] = f2h(vv.w > 0.f ? vv.w : 0.01f * vv.w);
                *(half4*)((_Float16*)Cq + go) = hv;
            } else {
                *(float4*)((float*)Cq + go) = vv;
            }
        }
    }
}

// ---------------------------------------------------------------------------
// Patch attention: one wave per patch-row n (8176 total), 4 waves/block.
// ---------------------------------------------------------------------------
#define TOP8_INS(mv) do { float _x = (mv); float _t;            \
    _t = fmaxf(s0,_x); _x = fminf(s0,_x); s0 = _t;              \
    _t = fmaxf(s1,_x); _x = fminf(s1,_x); s1 = _t;              \
    _t = fmaxf(s2,_x); _x = fminf(s2,_x); s2 = _t;              \
    _t = fmaxf(s3,_x); _x = fminf(s3,_x); s3 = _t;              \
    _t = fmaxf(s4,_x); _x = fminf(s4,_x); s4 = _t;              \
    _t = fmaxf(s5,_x); _x = fminf(s5,_x); s5 = _t;              \
    _t = fmaxf(s6,_x); _x = fminf(s6,_x); s6 = _t;              \
    s7 = fmaxf(s7,_x); } while (0)

__global__ __launch_bounds__(256) void patch_attn(
    const float* __restrict__ Xe,  const float* __restrict__ Wq,
    const float* __restrict__ Wk,  const float* __restrict__ Wv,
    const float* __restrict__ Wagg, const float* __restrict__ bagg,
    float* __restrict__ zout)
{
    __shared__ float sh[4][336];
    const int w    = threadIdx.x >> 6;
    const int lane = threadIdx.x & 63;
    const int n = blockIdx.x * 4 + w;   // 2044*4 = 8176 exactly
    const int b = n / 511;
    const int i = n - b * 511;
    float* pp  = &sh[w][0];
    float* qs  = pp + 64;
    float* ksm = pp + 128;
    float* vsm = pp + 192;
    float* avs = pp + 256;

    const float* xb = Xe + ((size_t)(b * 4096 + i * 8)) * 64 + lane;
    float s = 0.f;
#pragma unroll
    for (int p = 0; p < 16; p++) s += xb[(size_t)p * 64];
    pp[lane] = s * 0.0625f;
    __syncthreads();

    float q = 0.f, k = 0.f, v = 0.f;
#pragma unroll 4
    for (int e = 0; e < 64; e += 4) {
        float4 p4 = *(const float4*)&pp[e];
        q = fmaf(p4.x, Wq[(e+0)*64+lane], q); q = fmaf(p4.y, Wq[(e+1)*64+lane], q);
        q = fmaf(p4.z, Wq[(e+2)*64+lane], q); q = fmaf(p4.w, Wq[(e+3)*64+lane], q);
        k = fmaf(p4.x, Wk[(e+0)*64+lane], k); k = fmaf(p4.y, Wk[(e+1)*64+lane], k);
        k = fmaf(p4.z, Wk[(e+2)*64+lane], k); k = fmaf(p4.w, Wk[(e+3)*64+lane], k);
        v = fmaf(p4.x, Wv[(e+0)*64+lane], v); v = fmaf(p4.y, Wv[(e+1)*64+lane], v);
        v = fmaf(p4.z, Wv[(e+2)*64+lane], v); v = fmaf(p4.w, Wv[(e+3)*64+lane], v);
    }
    float sq = q * q, sk = k * k;
#pragma unroll
    for (int o = 1; o < 64; o <<= 1) { sq += __shfl_xor(sq, o); sk += __shfl_xor(sk, o); }
    const float qni = q / (sqrtf(sq) + 1e-8f);
    const float kni = k / (sqrtf(sk) + 1e-8f);
    qs[lane] = qni; ksm[lane] = kni; vsm[lane] = v;
    __syncthreads();

    auto MV = [&](float kj, float qj) { return fmaf(qni, kj, -(kni * qj)); };

    float s0=-1e30f,s1=-1e30f,s2=-1e30f,s3=-1e30f,s4=-1e30f,s5=-1e30f,s6=-1e30f,s7=-1e30f;
#pragma unroll
    for (int j = 0; j < 64; j += 4) {
        float4 k4 = *(const float4*)&ksm[j];
        float4 q4 = *(const float4*)&qs[j];
        TOP8_INS(MV(k4.x, q4.x)); TOP8_INS(MV(k4.y, q4.y));
        TOP8_INS(MV(k4.z, q4.z)); TOP8_INS(MV(k4.w, q4.w));
    }
    const float teff = fmaxf(s7, 1e-37f) * (1.f - 1.2e-7f);

    float ssum = 0.f, av = 0.f;
#pragma unroll
    for (int j = 0; j < 64; j += 4) {
        float4 k4 = *(const float4*)&ksm[j];
        float4 q4 = *(const float4*)&qs[j];
        float4 v4 = *(const float4*)&vsm[j];
#define P2(KJ, QJ, VJ) do { float _m = MV(KJ, QJ); float _x2 = _m * _m;           \
        float _a = _m * (15.f + _x2) * __builtin_amdgcn_rcpf(fmaf(6.f, _x2, 15.f)); \
        float _am = (_m >= teff) ? _a : 0.f;                                       \
        ssum += _am; av = fmaf(_am, (VJ), av); } while (0)
        P2(k4.x, q4.x, v4.x); P2(k4.y, q4.y, v4.y);
        P2(k4.z, q4.z, v4.z); P2(k4.w, q4.w, v4.w);
#undef P2
    }
    avs[lane] = av / fmaxf(ssum, 1e-8f);
    __syncthreads();

    float zc = bagg[lane];
#pragma unroll 4
    for (int e = 0; e < 64; e += 4) {
        float4 a4 = *(const float4*)&avs[e];
        zc = fmaf(a4.x, Wagg[(e+0)*64+lane], zc); zc = fmaf(a4.y, Wagg[(e+1)*64+lane], zc);
        zc = fmaf(a4.z, Wagg[(e+2)*64+lane], zc); zc = fmaf(a4.w, Wagg[(e+3)*64+lane], zc);
    }
    zc = zc > 0.f ? zc : 0.01f * zc;
    zout[(size_t)n * 64 + lane] = zc;
}

// ---------------------------------------------------------------------------
// Overlap-average scatter -> fp16 for dec GEMM
// ---------------------------------------------------------------------------
__global__ __launch_bounds__(256) void scatter_avg(
    const float* __restrict__ z, _Float16* __restrict__ zavg)
{
    const int idx = blockIdx.x * 256 + threadIdx.x;   // 16384 blocks -> 4194304
    const int c = idx & 63;
    const int l = (idx >> 6) & 4095;
    const int b = idx >> 18;
    const int g = l >> 3;
    float s = 0.f, cnt = 0.f;
    if (g >= 1)   { s += z[((size_t)(b * 511 + g - 1)) * 64 + c]; cnt += 1.f; }
    if (g <= 510) { s += z[((size_t)(b * 511 + g)) * 64 + c];     cnt += 1.f; }
    zavg[idx] = f2h(s / cnt);
}

// ---------------------------------------------------------------------------
extern "C" void kernel_launch(void* const* d_in, const int* in_sizes, int n_in,
                              void* d_out, int out_size, void* d_ws, size_t ws_size,
                              hipStream_t stream)
{
    const float* X    = (const float*)d_in[0];
    const float* W1   = (const float*)d_in[1];
    const float* b1   = (const float*)d_in[2];
    const float* W2   = (const float*)d_in[3];
    const float* b2   = (const float*)d_in[4];
    const float* Wq   = (const float*)d_in[5];
    const float* Wk   = (const float*)d_in[6];
    const float* Wv   = (const float*)d_in[7];
    const float* Wagg = (const float*)d_in[8];
    const float* bagg = (const float*)d_in[9];
    const float* Wd   = (const float*)d_in[10];
    const float* bd   = (const float*)d_in[11];

    char* ws = (char*)d_ws;
    _Float16* hidden = (_Float16*)(ws);                 // 65536x256 fp16  33,554,432 B
    float*    Xe     = (float*)(ws + 33554432);         // 65536x64  f32   16,777,216 B
    float*    z      = (float*)(ws + 50331648);         // 8176x64   f32    2,093,056 B
    _Float16* zavg   = (_Float16*)(ws + 52424704);      // 65536x64  fp16   8,388,608 B
    _Float16* W1t    = (_Float16*)(ws + 60813312);      // 256x512 fp16
    _Float16* W2t    = (_Float16*)(ws + 61075456);      // 64x256  fp16
    _Float16* Wdt    = (_Float16*)(ws + 61108224);      // 512x64  fp16
    float* out = (float*)d_out;

    prep_weights<<<512, 256, 0, stream>>>(W1, W2, Wd, W1t, W2t, Wdt);

    // enc1: hidden = leaky(X @ W1 + b1)   [fp16 out]
    gemm_kernel<128,128,64,64,true,0><<<dim3(2,512), 256, 0, stream>>>(
        X, W1t, b1, hidden, 65536, 256, 512, 512);
    // enc2: Xe = hidden @ W2 + b2         [f32 out]
    gemm_kernel<128,64,32,64,false,1><<<dim3(1,512), 256, 0, stream>>>(
        hidden, W2t, b2, Xe, 65536, 64, 256, 256);
    // patch attention -> z
    patch_attn<<<2044, 256, 0, stream>>>(Xe, Wq, Wk, Wv, Wagg, bagg, z);
    // overlap-average -> zavg (fp16)
    scatter_avg<<<16384, 256, 0, stream>>>(z, zavg);
    // dec: out = zavg @ Wd + bd           [f32 out]
    gemm_kernel<128,128,64,64,false,1><<<dim3(4,512), 256, 0, stream>>>(
        zavg, Wdt, bd, out, 65536, 512, 64, 64);
}

// Round 4
// 318.294 us; speedup vs baseline: 1.0829x; 1.0721x over previous
//
#include <hip/hip_runtime.h>

// ---------------------------------------------------------------------------
// X:(16,4096,512) -> M=65536 rows. enc1 K=512 N=256, enc2 K=256 N=64.
// h=511 patches/batch, N=8176 patch rows. dec K=64 N=512.
// ---------------------------------------------------------------------------

typedef __attribute__((ext_vector_type(8))) _Float16 half8;
typedef __attribute__((ext_vector_type(4))) _Float16 half4;
typedef __attribute__((ext_vector_type(4))) float floatx4;

__device__ __forceinline__ _Float16 f2h(float f) { return (_Float16)f; }

#define MFMA16(A, B, C) __builtin_amdgcn_mfma_f32_16x16x32_f16((A), (B), (C), 0, 0, 0)

// ---------------------------------------------------------------------------
// Prep: weights -> fp16 K-major: W1t[256][512], W2t[64][256], Wdt[512][64]
// ---------------------------------------------------------------------------
__global__ __launch_bounds__(256) void prep_weights(
    const float* __restrict__ W1, const float* __restrict__ W2,
    const float* __restrict__ Wd,
    _Float16* __restrict__ W1t, _Float16* __restrict__ W2t,
    _Float16* __restrict__ Wdt)
{
    int idx = blockIdx.x * 256 + threadIdx.x;           // 512 blocks -> 131072
    { int n = idx >> 9, k = idx & 511;  W1t[idx] = f2h(W1[k * 256 + n]); }
    if (idx < 16384) { int n = idx >> 8, k = idx & 255; W2t[idx] = f2h(W2[k * 64 + n]); }
    if (idx < 32768) { int n = idx >> 6, k = idx & 63;  Wdt[idx] = f2h(Wd[k * 512 + n]); }
}

// ---------------------------------------------------------------------------
// enc_fused: Xe[64x64 tile] = (leaky(X@W1+b1)) @ W2 + b2, one block per 64 rows.
//  Stage 1 (K=512, BK=64): OPERAND-SWAPPED MFMA (A=W1t rows c, B=X rows m) so
//  acc holds D[c][m]: lane = fixed m, regs = 4 consecutive c -> ds_write_b64
//  into row-major H[64][264] without a transpose.
//   - X staged via VGPR (fp32->fp16 cvt) into As[64][72] (padded).
//   - W1t staged via global_load_lds width=16 into Bs[256][64] unpadded,
//     XOR-swizzled chunks (swizzle applied on the per-lane SOURCE address;
//     DMA dst is wave-uniform base + lane*16B).
//  Stage 2 (K2=256 over 4 panels): Xe = H @ W2, W2 panel staged per-64-cols.
// LDS: stage1 As(9216)+Bs(32768)=41984 B; stage2 H(33792)+W2s(9216)=43008 B
// (aliased union, 43008 B total) -> ~3 blocks/CU LDS-wise.
// ---------------------------------------------------------------------------
__global__ __launch_bounds__(256) void enc_fused(
    const float* __restrict__ X, const _Float16* __restrict__ W1t,
    const float* __restrict__ b1, const _Float16* __restrict__ W2t,
    const float* __restrict__ b2, float* __restrict__ Xe)
{
    __shared__ _Float16 smem[21504];            // 43008 B
    _Float16* As  = smem;                       // [64][72]   (stage 1)
    _Float16* Bs  = smem + 4608;                // [256][64]  swizzled (stage 1)
    _Float16* Hs  = smem;                       // [64][264]  (stage 2)
    _Float16* W2s = smem + 16896;               // [64][72]   (stage 2)

    const int tid  = threadIdx.x;
    const int lane = tid & 63;
    const int w    = tid >> 6;
    const int m0   = blockIdx.x * 64;

    // ---- A (X) staging geometry: 4 threads/row, 16 fp32 each ----
    const int arow  = tid >> 2;                  // 0..63
    const int akseg = (tid & 3) << 4;            // 0,16,32,48
    const float* Abase = X + (size_t)(m0 + arow) * 512 + akseg;

    // ---- B (W1t) DMA geometry: per wave 8 insts x (64 lanes x 16B) ----
    const int brow0  = (w << 6) + (lane >> 3);                 // row for inst 0
    const int bchunk = (((lane & 7) ^ ((lane >> 3) & 7)) << 3);// swizzled src chunk (halfs)

    floatx4 acc1[4][4];
#pragma unroll
    for (int ci = 0; ci < 4; ci++)
#pragma unroll
        for (int mi = 0; mi < 4; mi++) acc1[ci][mi] = (floatx4){0.f, 0.f, 0.f, 0.f};

    float4 pa[4];
    auto loadA = [&](int kt) {
#pragma unroll
        for (int u = 0; u < 4; u++) pa[u] = *(const float4*)(Abase + kt + 4 * u);
    };

    loadA(0);
    for (int kt = 0; kt < 512; kt += 64) {
        // B: async DMA into swizzled Bs (drained by the next __syncthreads)
#pragma unroll
        for (int inst = 0; inst < 8; inst++) {
            const _Float16* src = W1t + (size_t)(brow0 + inst * 8) * 512 + kt + bchunk;
            __builtin_amdgcn_global_load_lds(
                (const __attribute__((address_space(1))) unsigned int*)src,
                (__attribute__((address_space(3))) unsigned int*)(Bs + ((w << 6) + inst * 8) * 64),
                16, 0, 0);
        }
        // A: cvt prefetched fp32 -> fp16, store to padded As
        {
            _Float16* d = &As[arow * 72 + akseg];
#pragma unroll
            for (int h = 0; h < 2; h++) {
                float4 f0 = pa[2 * h], f1 = pa[2 * h + 1];
                half8 o;
                o[0] = f2h(f0.x); o[1] = f2h(f0.y); o[2] = f2h(f0.z); o[3] = f2h(f0.w);
                o[4] = f2h(f1.x); o[5] = f2h(f1.y); o[6] = f2h(f1.z); o[7] = f2h(f1.w);
                *(half8*)(d + 8 * h) = o;
            }
        }
        __syncthreads();
        if (kt + 64 < 512) loadA(kt + 64);       // overlaps MFMA phase
#pragma unroll
        for (int ks = 0; ks < 2; ks++) {
            const int lchunk = ks * 4 + (lane >> 4);       // logical 8-half chunk
            half8 af[4], bf[4];
#pragma unroll
            for (int ci = 0; ci < 4; ci++) {
                const int c = (w << 6) + ci * 16 + (lane & 15);
                af[ci] = *(const half8*)&Bs[c * 64 + ((lchunk ^ (lane & 7)) << 3)];
            }
#pragma unroll
            for (int mi = 0; mi < 4; mi++)
                bf[mi] = *(const half8*)&As[(mi * 16 + (lane & 15)) * 72 + ks * 32 + ((lane >> 4) << 3)];
#pragma unroll
            for (int ci = 0; ci < 4; ci++)
#pragma unroll
                for (int mi = 0; mi < 4; mi++)
                    acc1[ci][mi] = MFMA16(af[ci], bf[mi], acc1[ci][mi]);
        }
        __syncthreads();
    }

    // ---- H = leaky(hidden + b1) -> LDS row-major [m][c], b64 stores ----
    float4 b1v[4];
#pragma unroll
    for (int ci = 0; ci < 4; ci++)
        b1v[ci] = *(const float4*)&b1[(w << 6) + ci * 16 + ((lane >> 4) << 2)];
#pragma unroll
    for (int ci = 0; ci < 4; ci++) {
        const int cb = (w << 6) + ci * 16 + ((lane >> 4) << 2);
#pragma unroll
        for (int mi = 0; mi < 4; mi++) {
            const int m = mi * 16 + (lane & 15);
            half4 hv;
#pragma unroll
            for (int r = 0; r < 4; r++) {
                float v = acc1[ci][mi][r] + ((const float*)&b1v[ci])[r];
                v = v > 0.f ? v : 0.01f * v;
                hv[r] = f2h(v);
            }
            *(half4*)&Hs[m * 264 + cb] = hv;
        }
    }

    // ---- stage 2: Xe = H @ W2 + b2 over 4 K-panels of 64 ----
    floatx4 acc2[4];
#pragma unroll
    for (int ni = 0; ni < 4; ni++) acc2[ni] = (floatx4){0.f, 0.f, 0.f, 0.f};
    const int w2n   = tid >> 2;                  // 0..63 (W2 out-channel row)
    const int w2seg = (tid & 3) << 4;
#pragma unroll
    for (int p = 0; p < 4; p++) {
        *(half8*)&W2s[w2n * 72 + w2seg]     = *(const half8*)&W2t[w2n * 256 + p * 64 + w2seg];
        *(half8*)&W2s[w2n * 72 + w2seg + 8] = *(const half8*)&W2t[w2n * 256 + p * 64 + w2seg + 8];
        __syncthreads();                          // H + W2 panel visible
#pragma unroll
        for (int ks = 0; ks < 2; ks++) {
            half8 a2 = *(const half8*)&Hs[((w << 4) + (lane & 15)) * 264 + p * 64 + ks * 32 + ((lane >> 4) << 3)];
            half8 b2f[4];
#pragma unroll
            for (int ni = 0; ni < 4; ni++)
                b2f[ni] = *(const half8*)&W2s[(ni * 16 + (lane & 15)) * 72 + ks * 32 + ((lane >> 4) << 3)];
#pragma unroll
            for (int ni = 0; ni < 4; ni++)
                acc2[ni] = MFMA16(a2, b2f[ni], acc2[ni]);
        }
        __syncthreads();                          // readers done before restage
    }
    // Xe store (fp32): wave w owns rows [16w..16w+16)
#pragma unroll
    for (int ni = 0; ni < 4; ni++) {
        const float bb = b2[ni * 16 + (lane & 15)];
#pragma unroll
        for (int r = 0; r < 4; r++) {
            const int row = m0 + (w << 4) + ((lane >> 4) << 2) + r;
            Xe[(size_t)row * 64 + ni * 16 + (lane & 15)] = acc2[ni][r] + bb;
        }
    }
}

// ---------------------------------------------------------------------------
// Patch attention (unchanged): one wave per patch-row n, 4 waves/block.
// ---------------------------------------------------------------------------
#define TOP8_INS(mv) do { float _x = (mv); float _t;            \
    _t = fmaxf(s0,_x); _x = fminf(s0,_x); s0 = _t;              \
    _t = fmaxf(s1,_x); _x = fminf(s1,_x); s1 = _t;              \
    _t = fmaxf(s2,_x); _x = fminf(s2,_x); s2 = _t;              \
    _t = fmaxf(s3,_x); _x = fminf(s3,_x); s3 = _t;              \
    _t = fmaxf(s4,_x); _x = fminf(s4,_x); s4 = _t;              \
    _t = fmaxf(s5,_x); _x = fminf(s5,_x); s5 = _t;              \
    _t = fmaxf(s6,_x); _x = fminf(s6,_x); s6 = _t;              \
    s7 = fmaxf(s7,_x); } while (0)

__global__ __launch_bounds__(256) void patch_attn(
    const float* __restrict__ Xe,  const float* __restrict__ Wq,
    const float* __restrict__ Wk,  const float* __restrict__ Wv,
    const float* __restrict__ Wagg, const float* __restrict__ bagg,
    float* __restrict__ zout)
{
    __shared__ float sh[4][336];
    const int w    = threadIdx.x >> 6;
    const int lane = threadIdx.x & 63;
    const int n = blockIdx.x * 4 + w;   // 2044*4 = 8176
    const int b = n / 511;
    const int i = n - b * 511;
    float* pp  = &sh[w][0];
    float* qs  = pp + 64;
    float* ksm = pp + 128;
    float* vsm = pp + 192;
    float* avs = pp + 256;

    const float* xb = Xe + ((size_t)(b * 4096 + i * 8)) * 64 + lane;
    float s = 0.f;
#pragma unroll
    for (int p = 0; p < 16; p++) s += xb[(size_t)p * 64];
    pp[lane] = s * 0.0625f;
    __syncthreads();

    float q = 0.f, k = 0.f, v = 0.f;
#pragma unroll 4
    for (int e = 0; e < 64; e += 4) {
        float4 p4 = *(const float4*)&pp[e];
        q = fmaf(p4.x, Wq[(e+0)*64+lane], q); q = fmaf(p4.y, Wq[(e+1)*64+lane], q);
        q = fmaf(p4.z, Wq[(e+2)*64+lane], q); q = fmaf(p4.w, Wq[(e+3)*64+lane], q);
        k = fmaf(p4.x, Wk[(e+0)*64+lane], k); k = fmaf(p4.y, Wk[(e+1)*64+lane], k);
        k = fmaf(p4.z, Wk[(e+2)*64+lane], k); k = fmaf(p4.w, Wk[(e+3)*64+lane], k);
        v = fmaf(p4.x, Wv[(e+0)*64+lane], v); v = fmaf(p4.y, Wv[(e+1)*64+lane], v);
        v = fmaf(p4.z, Wv[(e+2)*64+lane], v); v = fmaf(p4.w, Wv[(e+3)*64+lane], v);
    }
    float sq = q * q, sk = k * k;
#pragma unroll
    for (int o = 1; o < 64; o <<= 1) { sq += __shfl_xor(sq, o); sk += __shfl_xor(sk, o); }
    const float qni = q / (sqrtf(sq) + 1e-8f);
    const float kni = k / (sqrtf(sk) + 1e-8f);
    qs[lane] = qni; ksm[lane] = kni; vsm[lane] = v;
    __syncthreads();

    auto MV = [&](float kj, float qj) { return fmaf(qni, kj, -(kni * qj)); };

    float s0=-1e30f,s1=-1e30f,s2=-1e30f,s3=-1e30f,s4=-1e30f,s5=-1e30f,s6=-1e30f,s7=-1e30f;
#pragma unroll
    for (int j = 0; j < 64; j += 4) {
        float4 k4 = *(const float4*)&ksm[j];
        float4 q4 = *(const float4*)&qs[j];
        TOP8_INS(MV(k4.x, q4.x)); TOP8_INS(MV(k4.y, q4.y));
        TOP8_INS(MV(k4.z, q4.z)); TOP8_INS(MV(k4.w, q4.w));
    }
    const float teff = fmaxf(s7, 1e-37f) * (1.f - 1.2e-7f);

    float ssum = 0.f, av = 0.f;
#pragma unroll
    for (int j = 0; j < 64; j += 4) {
        float4 k4 = *(const float4*)&ksm[j];
        float4 q4 = *(const float4*)&qs[j];
        float4 v4 = *(const float4*)&vsm[j];
#define P2(KJ, QJ, VJ) do { float _m = MV(KJ, QJ); float _x2 = _m * _m;           \
        float _a = _m * (15.f + _x2) * __builtin_amdgcn_rcpf(fmaf(6.f, _x2, 15.f)); \
        float _am = (_m >= teff) ? _a : 0.f;                                       \
        ssum += _am; av = fmaf(_am, (VJ), av); } while (0)
        P2(k4.x, q4.x, v4.x); P2(k4.y, q4.y, v4.y);
        P2(k4.z, q4.z, v4.z); P2(k4.w, q4.w, v4.w);
#undef P2
    }
    avs[lane] = av / fmaxf(ssum, 1e-8f);
    __syncthreads();

    float zc = bagg[lane];
#pragma unroll 4
    for (int e = 0; e < 64; e += 4) {
        float4 a4 = *(const float4*)&avs[e];
        zc = fmaf(a4.x, Wagg[(e+0)*64+lane], zc); zc = fmaf(a4.y, Wagg[(e+1)*64+lane], zc);
        zc = fmaf(a4.z, Wagg[(e+2)*64+lane], zc); zc = fmaf(a4.w, Wagg[(e+3)*64+lane], zc);
    }
    zc = zc > 0.f ? zc : 0.01f * zc;
    zout[(size_t)n * 64 + lane] = zc;
}

// ---------------------------------------------------------------------------
// dec_fused: out[128x128 tile] = blend2(z)[128x64] @ Wd + bd.
//  A-stage builds the overlap-averaged patch feature on the fly:
//  row l covered by patches {g-1, g} (g=l>>3) clipped to [0,510].
//  K=64: single tile, then chunked-LDS float4 epilogue.
// ---------------------------------------------------------------------------
__global__ __launch_bounds__(256) void dec_fused(
    const float* __restrict__ z, const _Float16* __restrict__ Wdt,
    const float* __restrict__ bd, float* __restrict__ out)
{
    __shared__ _Float16 As[128 * 72];
    __shared__ _Float16 Bs[128 * 72];
    const int tid  = threadIdx.x;
    const int lane = tid & 63;
    const int w    = tid >> 6;
    const int m0 = blockIdx.y * 128, n0 = blockIdx.x * 128;
    const int wrow = (w & 1) << 6, wcol = (w >> 1) << 6;

    // ---- A: blended zavg rows (2 threads/row, 32 elems each) ----
    {
        const int arow  = tid >> 1;
        const int akseg = (tid & 1) << 5;
        const int row = m0 + arow;
        const int b = row >> 12, l = row & 4095, g = l >> 3;
        const int g0 = g - 1 >= 0 ? g - 1 : 0;
        const int g1 = g <= 510 ? g : 510;
        const float w0 = (g >= 1) ? 1.f : 0.f;
        const float w1 = (g <= 510) ? 1.f : 0.f;
        const float sc = (w0 + w1) > 1.5f ? 0.5f : 1.f;
        const float* z0 = z + ((size_t)(b * 511 + g0)) * 64 + akseg;
        const float* z1 = z + ((size_t)(b * 511 + g1)) * 64 + akseg;
        _Float16* d = &As[arow * 72 + akseg];
#pragma unroll
        for (int u = 0; u < 4; u++) {
            float4 f0a = *(const float4*)(z0 + 8 * u);
            float4 f0b = *(const float4*)(z0 + 8 * u + 4);
            float4 f1a = *(const float4*)(z1 + 8 * u);
            float4 f1b = *(const float4*)(z1 + 8 * u + 4);
            half8 o;
            o[0] = f2h((f0a.x * w0 + f1a.x * w1) * sc);
            o[1] = f2h((f0a.y * w0 + f1a.y * w1) * sc);
            o[2] = f2h((f0a.z * w0 + f1a.z * w1) * sc);
            o[3] = f2h((f0a.w * w0 + f1a.w * w1) * sc);
            o[4] = f2h((f0b.x * w0 + f1b.x * w1) * sc);
            o[5] = f2h((f0b.y * w0 + f1b.y * w1) * sc);
            o[6] = f2h((f0b.z * w0 + f1b.z * w1) * sc);
            o[7] = f2h((f0b.w * w0 + f1b.w * w1) * sc);
            *(half8*)(d + 8 * u) = o;
        }
    }
    // ---- B: Wdt rows ----
    {
        const int brow  = tid >> 1;
        const int bkseg = (tid & 1) << 5;
        const _Float16* s = Wdt + (size_t)(n0 + brow) * 64 + bkseg;
        _Float16* d = &Bs[brow * 72 + bkseg];
#pragma unroll
        for (int u = 0; u < 4; u++) *(half8*)(d + 8 * u) = *(const half8*)(s + 8 * u);
    }
    __syncthreads();

    floatx4 acc[2][4];   // MI=... wave tile 64x64 -> MI=4? see below
    // wave tile: WM=64, WN=64 -> MI=4, NI=4
    floatx4 accf[4][4];
#pragma unroll
    for (int mi = 0; mi < 4; mi++)
#pragma unroll
        for (int ni = 0; ni < 4; ni++) accf[mi][ni] = (floatx4){0.f, 0.f, 0.f, 0.f};
    (void)acc;
#pragma unroll
    for (int ks = 0; ks < 2; ks++) {
        const int koff = ks * 32 + ((lane >> 4) << 3);
        half8 af[4], bf[4];
#pragma unroll
        for (int mi = 0; mi < 4; mi++)
            af[mi] = *(const half8*)&As[(wrow + mi * 16 + (lane & 15)) * 72 + koff];
#pragma unroll
        for (int ni = 0; ni < 4; ni++)
            bf[ni] = *(const half8*)&Bs[(wcol + ni * 16 + (lane & 15)) * 72 + koff];
#pragma unroll
        for (int mi = 0; mi < 4; mi++)
#pragma unroll
            for (int ni = 0; ni < 4; ni++)
                accf[mi][ni] = MFMA16(af[mi], bf[ni], accf[mi][ni]);
    }

    // ---- epilogue: 32-row chunks in LDS -> coalesced float4 stores ----
    float bvv[4];
#pragma unroll
    for (int ni = 0; ni < 4; ni++) bvv[ni] = bd[n0 + wcol + ni * 16 + (lane & 15)];

    float* Cs = (float*)As;                       // 32*128*4 = 16384 B <= As
#pragma unroll
    for (int c = 0; c < 4; c++) {
        __syncthreads();
        const int own_wrow = ((c * 32) / 64) * 64;
        if (wrow == own_wrow) {
#pragma unroll
            for (int mm = 0; mm < 2; mm++) {
                const int mi = ((c * 32) % 64) / 16 + mm;
#pragma unroll
                for (int ni = 0; ni < 4; ni++) {
#pragma unroll
                    for (int r = 0; r < 4; r++) {
                        const int lr  = mm * 16 + ((lane >> 4) << 2) + r;
                        const int col = wcol + ni * 16 + (lane & 15);
                        Cs[lr * 128 + col] = accf[mi][ni][r] + bvv[ni];
                    }
                }
            }
        }
        __syncthreads();
#pragma unroll
        for (int u = 0; u < 4; u++) {
            const int idx = (u * 256 + tid) * 4;
            const int lr = idx >> 7, col = idx & 127;
            float4 vv = *(const float4*)&Cs[idx];
            *(float4*)&out[(size_t)(m0 + c * 32 + lr) * 512 + n0 + col] = vv;
        }
    }
}

// ---------------------------------------------------------------------------
extern "C" void kernel_launch(void* const* d_in, const int* in_sizes, int n_in,
                              void* d_out, int out_size, void* d_ws, size_t ws_size,
                              hipStream_t stream)
{
    const float* X    = (const float*)d_in[0];
    const float* W1   = (const float*)d_in[1];
    const float* b1   = (const float*)d_in[2];
    const float* W2   = (const float*)d_in[3];
    const float* b2   = (const float*)d_in[4];
    const float* Wq   = (const float*)d_in[5];
    const float* Wk   = (const float*)d_in[6];
    const float* Wv   = (const float*)d_in[7];
    const float* Wagg = (const float*)d_in[8];
    const float* bagg = (const float*)d_in[9];
    const float* Wd   = (const float*)d_in[10];
    const float* bd   = (const float*)d_in[11];

    char* ws = (char*)d_ws;
    float*    Xe  = (float*)(ws);                  // 65536x64 f32   16,777,216 B
    float*    z   = (float*)(ws + 16777216);       // 8176x64  f32    2,093,056 B
    _Float16* W1t = (_Float16*)(ws + 18870272);    // 256x512 fp16      262,144 B
    _Float16* W2t = (_Float16*)(ws + 19132416);    // 64x256  fp16       32,768 B
    _Float16* Wdt = (_Float16*)(ws + 19165184);    // 512x64  fp16       65,536 B
    float* out = (float*)d_out;

    prep_weights<<<512, 256, 0, stream>>>(W1, W2, Wd, W1t, W2t, Wdt);
    enc_fused<<<1024, 256, 0, stream>>>(X, W1t, b1, W2t, b2, Xe);
    patch_attn<<<2044, 256, 0, stream>>>(Xe, Wq, Wk, Wv, Wagg, bagg, z);
    dec_fused<<<dim3(4, 512), 256, 0, stream>>>(z, Wdt, bd, out);
}

// Round 5
// 317.416 us; speedup vs baseline: 1.0859x; 1.0028x over previous
//
#include <hip/hip_runtime.h>

// ---------------------------------------------------------------------------
// X:(16,4096,512) -> M=65536 rows. enc1 K=512 N=256, d=64.
// h=511 patches/batch, 512 8-row groups/batch (patch i = groups i,i+1).
// Xe is never needed per-element: only per-patch means -> per-group sums Gs.
// ---------------------------------------------------------------------------

typedef __attribute__((ext_vector_type(8))) _Float16 half8;
typedef __attribute__((ext_vector_type(4))) _Float16 half4;
typedef __attribute__((ext_vector_type(4))) float floatx4;

__device__ __forceinline__ _Float16 f2h(float f) { return (_Float16)f; }

#define MFMA16(A, B, C) __builtin_amdgcn_mfma_f32_16x16x32_f16((A), (B), (C), 0, 0, 0)

// ---------------------------------------------------------------------------
// Prep: weights -> fp16 K-major: W1t[256][512], W2t[64][256], Wdt[512][64]
// ---------------------------------------------------------------------------
__global__ __launch_bounds__(256) void prep_weights(
    const float* __restrict__ W1, const float* __restrict__ W2,
    const float* __restrict__ Wd,
    _Float16* __restrict__ W1t, _Float16* __restrict__ W2t,
    _Float16* __restrict__ Wdt)
{
    int idx = blockIdx.x * 256 + threadIdx.x;           // 512 blocks -> 131072
    { int n = idx >> 9, k = idx & 511;  W1t[idx] = f2h(W1[k * 256 + n]); }
    if (idx < 16384) { int n = idx >> 8, k = idx & 255; W2t[idx] = f2h(W2[k * 64 + n]); }
    if (idx < 32768) { int n = idx >> 6, k = idx & 63;  Wdt[idx] = f2h(Wd[k * 512 + n]); }
}

// ---------------------------------------------------------------------------
// enc_fused: Gs[8 groups][64] per 64-row block.
//  Stage 1 (K=512, BK=64): operand-swapped MFMA -> acc D[c][m]
//   (c: row=(lane>>4)*4+r within ci*16 (+w*64); m: col=lane&15 within mi*16).
//   X staged via VGPR cvt into As[64][72]; W1t via global_load_lds width=16
//   into Bs[256][64] with XOR-chunk source swizzle.
//  Group-reduce: leaky(hidden+b1), butterfly shfl_xor(1,2,4) sums m over each
//   8-row group (m = lane bits 0..3), writers (lane&7)==0 -> Hsum fp16 LDS.
//  Stage 2: Gs = Hsum[8pad16][256] @ W2 + 8*b2 -- 8 MFMAs/wave, W2t read
//   direct from global (L2-hot). Garbage Hsum rows 8-15 only affect D rows
//   8-15 (never stored) -- MFMA rows are independent.
// ---------------------------------------------------------------------------
__global__ __launch_bounds__(256) void enc_fused(
    const float* __restrict__ X, const _Float16* __restrict__ W1t,
    const float* __restrict__ b1, const _Float16* __restrict__ W2t,
    const float* __restrict__ b2, float* __restrict__ Gs)
{
    __shared__ _Float16 smem[20992];            // 41984 B
    _Float16* As   = smem;                      // [64][72]   stage 1
    _Float16* Bs   = smem + 4608;               // [256][64]  stage 1 (swizzled)
    _Float16* Hs16 = smem;                      // [16][264]  stage 2 (rows 0-7 valid)

    const int tid  = threadIdx.x;
    const int lane = tid & 63;
    const int w    = tid >> 6;
    const int m0   = blockIdx.x * 64;

    const int arow  = tid >> 2;                  // 0..63
    const int akseg = (tid & 3) << 4;            // 0,16,32,48
    const float* Abase = X + (size_t)(m0 + arow) * 512 + akseg;

    const int brow0  = (w << 6) + (lane >> 3);
    const int bchunk = (((lane & 7) ^ ((lane >> 3) & 7)) << 3);

    floatx4 acc1[4][4];
#pragma unroll
    for (int ci = 0; ci < 4; ci++)
#pragma unroll
        for (int mi = 0; mi < 4; mi++) acc1[ci][mi] = (floatx4){0.f, 0.f, 0.f, 0.f};

    float4 pa[4];
    auto loadA = [&](int kt) {
#pragma unroll
        for (int u = 0; u < 4; u++) pa[u] = *(const float4*)(Abase + kt + 4 * u);
    };

    loadA(0);
    for (int kt = 0; kt < 512; kt += 64) {
#pragma unroll
        for (int inst = 0; inst < 8; inst++) {
            const _Float16* src = W1t + (size_t)(brow0 + inst * 8) * 512 + kt + bchunk;
            __builtin_amdgcn_global_load_lds(
                (const __attribute__((address_space(1))) unsigned int*)src,
                (__attribute__((address_space(3))) unsigned int*)(Bs + ((w << 6) + inst * 8) * 64),
                16, 0, 0);
        }
        {
            _Float16* d = &As[arow * 72 + akseg];
#pragma unroll
            for (int h = 0; h < 2; h++) {
                float4 f0 = pa[2 * h], f1 = pa[2 * h + 1];
                half8 o;
                o[0] = f2h(f0.x); o[1] = f2h(f0.y); o[2] = f2h(f0.z); o[3] = f2h(f0.w);
                o[4] = f2h(f1.x); o[5] = f2h(f1.y); o[6] = f2h(f1.z); o[7] = f2h(f1.w);
                *(half8*)(d + 8 * h) = o;
            }
        }
        __syncthreads();
        if (kt + 64 < 512) loadA(kt + 64);
#pragma unroll
        for (int ks = 0; ks < 2; ks++) {
            const int lchunk = ks * 4 + (lane >> 4);
            half8 af[4], bf[4];
#pragma unroll
            for (int ci = 0; ci < 4; ci++) {
                const int c = (w << 6) + ci * 16 + (lane & 15);
                af[ci] = *(const half8*)&Bs[c * 64 + ((lchunk ^ (lane & 7)) << 3)];
            }
#pragma unroll
            for (int mi = 0; mi < 4; mi++)
                bf[mi] = *(const half8*)&As[(mi * 16 + (lane & 15)) * 72 + ks * 32 + ((lane >> 4) << 3)];
#pragma unroll
            for (int ci = 0; ci < 4; ci++)
#pragma unroll
                for (int mi = 0; mi < 4; mi++)
                    acc1[ci][mi] = MFMA16(af[ci], bf[mi], acc1[ci][mi]);
        }
        __syncthreads();
    }

    // ---- group-reduce: Hsum[g][c] = sum_{m in g} leaky(hidden[m][c]+b1[c]) ----
    float4 b1v[4];
#pragma unroll
    for (int ci = 0; ci < 4; ci++)
        b1v[ci] = *(const float4*)&b1[(w << 6) + ci * 16 + ((lane >> 4) << 2)];
#pragma unroll
    for (int ci = 0; ci < 4; ci++) {
#pragma unroll
        for (int mi = 0; mi < 4; mi++) {
            float vs[4];
#pragma unroll
            for (int r = 0; r < 4; r++) {
                float v = acc1[ci][mi][r] + ((const float*)&b1v[ci])[r];
                vs[r] = v > 0.f ? v : 0.01f * v;
            }
#pragma unroll
            for (int r = 0; r < 4; r++) {
                vs[r] += __shfl_xor(vs[r], 1);
                vs[r] += __shfl_xor(vs[r], 2);
                vs[r] += __shfl_xor(vs[r], 4);
            }
            if ((lane & 7) == 0) {
                const int gl = 2 * mi + ((lane & 15) >> 3);
                half4 hv;
#pragma unroll
                for (int r = 0; r < 4; r++) hv[r] = f2h(vs[r]);
                *(half4*)&Hs16[gl * 264 + (w << 6) + ci * 16 + ((lane >> 4) << 2)] = hv;
            }
        }
    }
    __syncthreads();

    // ---- stage 2: Gs = Hsum @ W2 + 8*b2 (each wave: 16 out-channels) ----
    floatx4 acc2 = (floatx4){0.f, 0.f, 0.f, 0.f};
    const int kq = (lane >> 4) << 3;
#pragma unroll
    for (int ks = 0; ks < 8; ks++) {
        half8 af = *(const half8*)&Hs16[(lane & 15) * 264 + ks * 32 + kq];
        half8 bf = *(const half8*)&W2t[(size_t)((w << 4) + (lane & 15)) * 256 + ks * 32 + kq];
        acc2 = MFMA16(af, bf, acc2);
    }
    if (lane < 32) {
        const int n = (w << 4) + (lane & 15);
        const float bb = 8.f * b2[n];
        const int gbase = blockIdx.x * 8;
#pragma unroll
        for (int r = 0; r < 4; r++) {
            const int g = ((lane >> 4) << 2) + r;          // 0..7
            Gs[(size_t)(gbase + g) * 64 + n] = acc2[r] + bb;
        }
    }
}

// ---------------------------------------------------------------------------
// Patch attention: one wave per patch-row n, 4 waves/block.
// pp = (Gs[b*512+i] + Gs[b*512+i+1]) / 16.
// ---------------------------------------------------------------------------
#define TOP8_INS(mv) do { float _x = (mv); float _t;            \
    _t = fmaxf(s0,_x); _x = fminf(s0,_x); s0 = _t;              \
    _t = fmaxf(s1,_x); _x = fminf(s1,_x); s1 = _t;              \
    _t = fmaxf(s2,_x); _x = fminf(s2,_x); s2 = _t;              \
    _t = fmaxf(s3,_x); _x = fminf(s3,_x); s3 = _t;              \
    _t = fmaxf(s4,_x); _x = fminf(s4,_x); s4 = _t;              \
    _t = fmaxf(s5,_x); _x = fminf(s5,_x); s5 = _t;              \
    _t = fmaxf(s6,_x); _x = fminf(s6,_x); s6 = _t;              \
    s7 = fmaxf(s7,_x); } while (0)

__global__ __launch_bounds__(256) void patch_attn(
    const float* __restrict__ Gs,  const float* __restrict__ Wq,
    const float* __restrict__ Wk,  const float* __restrict__ Wv,
    const float* __restrict__ Wagg, const float* __restrict__ bagg,
    float* __restrict__ zout)
{
    __shared__ float sh[4][336];
    const int w    = threadIdx.x >> 6;
    const int lane = threadIdx.x & 63;
    const int n = blockIdx.x * 4 + w;   // 2044*4 = 8176
    const int b = n / 511;
    const int i = n - b * 511;
    float* pp  = &sh[w][0];
    float* qs  = pp + 64;
    float* ksm = pp + 128;
    float* vsm = pp + 192;
    float* avs = pp + 256;

    const float* gp = Gs + ((size_t)(b * 512 + i)) * 64 + lane;
    pp[lane] = (gp[0] + gp[64]) * 0.0625f;
    __syncthreads();

    float q = 0.f, k = 0.f, v = 0.f;
#pragma unroll 4
    for (int e = 0; e < 64; e += 4) {
        float4 p4 = *(const float4*)&pp[e];
        q = fmaf(p4.x, Wq[(e+0)*64+lane], q); q = fmaf(p4.y, Wq[(e+1)*64+lane], q);
        q = fmaf(p4.z, Wq[(e+2)*64+lane], q); q = fmaf(p4.w, Wq[(e+3)*64+lane], q);
        k = fmaf(p4.x, Wk[(e+0)*64+lane], k); k = fmaf(p4.y, Wk[(e+1)*64+lane], k);
        k = fmaf(p4.z, Wk[(e+2)*64+lane], k); k = fmaf(p4.w, Wk[(e+3)*64+lane], k);
        v = fmaf(p4.x, Wv[(e+0)*64+lane], v); v = fmaf(p4.y, Wv[(e+1)*64+lane], v);
        v = fmaf(p4.z, Wv[(e+2)*64+lane], v); v = fmaf(p4.w, Wv[(e+3)*64+lane], v);
    }
    float sq = q * q, sk = k * k;
#pragma unroll
    for (int o = 1; o < 64; o <<= 1) { sq += __shfl_xor(sq, o); sk += __shfl_xor(sk, o); }
    const float qni = q / (sqrtf(sq) + 1e-8f);
    const float kni = k / (sqrtf(sk) + 1e-8f);
    qs[lane] = qni; ksm[lane] = kni; vsm[lane] = v;
    __syncthreads();

    auto MV = [&](float kj, float qj) { return fmaf(qni, kj, -(kni * qj)); };

    float s0=-1e30f,s1=-1e30f,s2=-1e30f,s3=-1e30f,s4=-1e30f,s5=-1e30f,s6=-1e30f,s7=-1e30f;
#pragma unroll
    for (int j = 0; j < 64; j += 4) {
        float4 k4 = *(const float4*)&ksm[j];
        float4 q4 = *(const float4*)&qs[j];
        TOP8_INS(MV(k4.x, q4.x)); TOP8_INS(MV(k4.y, q4.y));
        TOP8_INS(MV(k4.z, q4.z)); TOP8_INS(MV(k4.w, q4.w));
    }
    const float teff = fmaxf(s7, 1e-37f) * (1.f - 1.2e-7f);

    float ssum = 0.f, av = 0.f;
#pragma unroll
    for (int j = 0; j < 64; j += 4) {
        float4 k4 = *(const float4*)&ksm[j];
        float4 q4 = *(const float4*)&qs[j];
        float4 v4 = *(const float4*)&vsm[j];
#define P2(KJ, QJ, VJ) do { float _m = MV(KJ, QJ); float _x2 = _m * _m;           \
        float _a = _m * (15.f + _x2) * __builtin_amdgcn_rcpf(fmaf(6.f, _x2, 15.f)); \
        float _am = (_m >= teff) ? _a : 0.f;                                       \
        ssum += _am; av = fmaf(_am, (VJ), av); } while (0)
        P2(k4.x, q4.x, v4.x); P2(k4.y, q4.y, v4.y);
        P2(k4.z, q4.z, v4.z); P2(k4.w, q4.w, v4.w);
#undef P2
    }
    avs[lane] = av / fmaxf(ssum, 1e-8f);
    __syncthreads();

    float zc = bagg[lane];
#pragma unroll 4
    for (int e = 0; e < 64; e += 4) {
        float4 a4 = *(const float4*)&avs[e];
        zc = fmaf(a4.x, Wagg[(e+0)*64+lane], zc); zc = fmaf(a4.y, Wagg[(e+1)*64+lane], zc);
        zc = fmaf(a4.z, Wagg[(e+2)*64+lane], zc); zc = fmaf(a4.w, Wagg[(e+3)*64+lane], zc);
    }
    zc = zc > 0.f ? zc : 0.01f * zc;
    zout[(size_t)n * 64 + lane] = zc;
}

// ---------------------------------------------------------------------------
// dec_fused: out[128x128 tile] = blend2(z)[128x64] @ Wd + bd.
// ---------------------------------------------------------------------------
__global__ __launch_bounds__(256) void dec_fused(
    const float* __restrict__ z, const _Float16* __restrict__ Wdt,
    const float* __restrict__ bd, float* __restrict__ out)
{
    __shared__ _Float16 As[128 * 72];
    __shared__ _Float16 Bs[128 * 72];
    const int tid  = threadIdx.x;
    const int lane = tid & 63;
    const int w    = tid >> 6;
    const int m0 = blockIdx.y * 128, n0 = blockIdx.x * 128;
    const int wrow = (w & 1) << 6, wcol = (w >> 1) << 6;

    {
        const int arow  = tid >> 1;
        const int akseg = (tid & 1) << 5;
        const int row = m0 + arow;
        const int b = row >> 12, l = row & 4095, g = l >> 3;
        const int g0 = g - 1 >= 0 ? g - 1 : 0;
        const int g1 = g <= 510 ? g : 510;
        const float w0 = (g >= 1) ? 1.f : 0.f;
        const float w1 = (g <= 510) ? 1.f : 0.f;
        const float sc = (w0 + w1) > 1.5f ? 0.5f : 1.f;
        const float* z0 = z + ((size_t)(b * 511 + g0)) * 64 + akseg;
        const float* z1 = z + ((size_t)(b * 511 + g1)) * 64 + akseg;
        _Float16* d = &As[arow * 72 + akseg];
#pragma unroll
        for (int u = 0; u < 4; u++) {
            float4 f0a = *(const float4*)(z0 + 8 * u);
            float4 f0b = *(const float4*)(z0 + 8 * u + 4);
            float4 f1a = *(const float4*)(z1 + 8 * u);
            float4 f1b = *(const float4*)(z1 + 8 * u + 4);
            half8 o;
            o[0] = f2h((f0a.x * w0 + f1a.x * w1) * sc);
            o[1] = f2h((f0a.y * w0 + f1a.y * w1) * sc);
            o[2] = f2h((f0a.z * w0 + f1a.z * w1) * sc);
            o[3] = f2h((f0a.w * w0 + f1a.w * w1) * sc);
            o[4] = f2h((f0b.x * w0 + f1b.x * w1) * sc);
            o[5] = f2h((f0b.y * w0 + f1b.y * w1) * sc);
            o[6] = f2h((f0b.z * w0 + f1b.z * w1) * sc);
            o[7] = f2h((f0b.w * w0 + f1b.w * w1) * sc);
            *(half8*)(d + 8 * u) = o;
        }
    }
    {
        const int brow  = tid >> 1;
        const int bkseg = (tid & 1) << 5;
        const _Float16* s = Wdt + (size_t)(n0 + brow) * 64 + bkseg;
        _Float16* d = &Bs[brow * 72 + bkseg];
#pragma unroll
        for (int u = 0; u < 4; u++) *(half8*)(d + 8 * u) = *(const half8*)(s + 8 * u);
    }
    __syncthreads();

    floatx4 accf[4][4];
#pragma unroll
    for (int mi = 0; mi < 4; mi++)
#pragma unroll
        for (int ni = 0; ni < 4; ni++) accf[mi][ni] = (floatx4){0.f, 0.f, 0.f, 0.f};
#pragma unroll
    for (int ks = 0; ks < 2; ks++) {
        const int koff = ks * 32 + ((lane >> 4) << 3);
        half8 af[4], bf[4];
#pragma unroll
        for (int mi = 0; mi < 4; mi++)
            af[mi] = *(const half8*)&As[(wrow + mi * 16 + (lane & 15)) * 72 + koff];
#pragma unroll
        for (int ni = 0; ni < 4; ni++)
            bf[ni] = *(const half8*)&Bs[(wcol + ni * 16 + (lane & 15)) * 72 + koff];
#pragma unroll
        for (int mi = 0; mi < 4; mi++)
#pragma unroll
            for (int ni = 0; ni < 4; ni++)
                accf[mi][ni] = MFMA16(af[mi], bf[ni], accf[mi][ni]);
    }

    float bvv[4];
#pragma unroll
    for (int ni = 0; ni < 4; ni++) bvv[ni] = bd[n0 + wcol + ni * 16 + (lane & 15)];

    float* Cs = (float*)As;
#pragma unroll
    for (int c = 0; c < 4; c++) {
        __syncthreads();
        const int own_wrow = ((c * 32) / 64) * 64;
        if (wrow == own_wrow) {
#pragma unroll
            for (int mm = 0; mm < 2; mm++) {
                const int mi = ((c * 32) % 64) / 16 + mm;
#pragma unroll
                for (int ni = 0; ni < 4; ni++) {
#pragma unroll
                    for (int r = 0; r < 4; r++) {
                        const int lr  = mm * 16 + ((lane >> 4) << 2) + r;
                        const int col = wcol + ni * 16 + (lane & 15);
                        Cs[lr * 128 + col] = accf[mi][ni][r] + bvv[ni];
                    }
                }
            }
        }
        __syncthreads();
#pragma unroll
        for (int u = 0; u < 4; u++) {
            const int idx = (u * 256 + tid) * 4;
            const int lr = idx >> 7, col = idx & 127;
            float4 vv = *(const float4*)&Cs[idx];
            *(float4*)&out[(size_t)(m0 + c * 32 + lr) * 512 + n0 + col] = vv;
        }
    }
}

// ---------------------------------------------------------------------------
extern "C" void kernel_launch(void* const* d_in, const int* in_sizes, int n_in,
                              void* d_out, int out_size, void* d_ws, size_t ws_size,
                              hipStream_t stream)
{
    const float* X    = (const float*)d_in[0];
    const float* W1   = (const float*)d_in[1];
    const float* b1   = (const float*)d_in[2];
    const float* W2   = (const float*)d_in[3];
    const float* b2   = (const float*)d_in[4];
    const float* Wq   = (const float*)d_in[5];
    const float* Wk   = (const float*)d_in[6];
    const float* Wv   = (const float*)d_in[7];
    const float* Wagg = (const float*)d_in[8];
    const float* bagg = (const float*)d_in[9];
    const float* Wd   = (const float*)d_in[10];
    const float* bd   = (const float*)d_in[11];

    char* ws = (char*)d_ws;
    float*    Gs  = (float*)(ws);                  // 8192x64 f32  2,097,152 B
    float*    z   = (float*)(ws + 2097152);        // 8176x64 f32  2,093,056 B
    _Float16* W1t = (_Float16*)(ws + 4194304);     // 256x512 fp16   262,144 B
    _Float16* W2t = (_Float16*)(ws + 4456448);     // 64x256  fp16    32,768 B
    _Float16* Wdt = (_Float16*)(ws + 4489216);     // 512x64  fp16    65,536 B
    float* out = (float*)d_out;

    prep_weights<<<512, 256, 0, stream>>>(W1, W2, Wd, W1t, W2t, Wdt);
    enc_fused<<<1024, 256, 0, stream>>>(X, W1t, b1, W2t, b2, Gs);
    patch_attn<<<2044, 256, 0, stream>>>(Gs, Wq, Wk, Wv, Wagg, bagg, z);
    dec_fused<<<dim3(4, 512), 256, 0, stream>>>(z, Wdt, bd, out);
}